// Round 9
// baseline (179.633 us; speedup 1.0000x reference)
//
#include <hip/hip_runtime.h>

// ---------------------------------------------------------------------------
// MSAAttention fused pipeline (MI355X / gfx950), bf16 MFMA throughout.
//
// out = concat[softmax(qk^T*s)v @ w_merge + b_merge, ib] @ w_proj + b_proj
// Folded: wcombT holds (w_merge@w_proj_top)^T and w_proj_bot^T — the merge
// GEMM is deleted; biasc = b_merge@w_proj_top + b_proj.
// SCALE*log2e folded into q; softmax in exp2 domain, no max-subtraction.
// attn: R5 structure verbatim (robust best: 47.0 µs; R6 occupancy x2, R7
// acc-seed, R8 phase-stagger all null-to-negative).
// gemm_bt: BK 32 -> 64. Halves the number of {barrier, stage, barrier}
// K-slabs (qkv 8->4, out-proj 24->12, small 16->8) — attacks the barrier
// drain that dominates the thin-slab GEMMs (~129 µs of the 176 total is
// non-attn). Per-slab: 2x MFMA, 2x ds_read; LDS stride 72 u16 (2-way bank
// aliasing = free). Prefetch regs 2x (pre[8] = 32 VGPR) — still ~110 live.
// ---------------------------------------------------------------------------

typedef unsigned short u16;
typedef unsigned int u32;
typedef __bf16 bf16x8 __attribute__((ext_vector_type(8)));
typedef u16 su16x8 __attribute__((ext_vector_type(8)));
typedef u16 su16x4 __attribute__((ext_vector_type(4)));
typedef u32 u32x4 __attribute__((ext_vector_type(4)));
typedef float f32x4 __attribute__((ext_vector_type(4)));
typedef float f32x16 __attribute__((ext_vector_type(16)));

__device__ __forceinline__ u16 f2bf(float f) {
  union { __bf16 h; u16 u; } v;
  v.h = (__bf16)f;
  return v.u;
}

__device__ __forceinline__ float fexp2(float x) {
#if __has_builtin(__builtin_amdgcn_exp2f)
  return __builtin_amdgcn_exp2f(x);
#else
  return __expf(x * 0.6931471805599453f);
#endif
}

__device__ __forceinline__ f32x4 zero4() {
  f32x4 v = {0.f, 0.f, 0.f, 0.f};
  return v;
}

__device__ __forceinline__ f32x4 mfma16(bf16x8 a, bf16x8 b, f32x4 c) {
  return __builtin_amdgcn_mfma_f32_16x16x32_bf16(a, b, c, 0, 0, 0);
}

__device__ __forceinline__ f32x16 mfma32(bf16x8 a, bf16x8 b, f32x16 c) {
  return __builtin_amdgcn_mfma_f32_32x32x16_bf16(a, b, c, 0, 0, 0);
}

// pack two f32 -> one u32 of two bf16 (lo = a, hi = b)
__device__ __forceinline__ u32 pkbf(float a, float b) {
  u32 r;
  asm("v_cvt_pk_bf16_f32 %0, %1, %2" : "=v"(r) : "v"(a), "v"(b));
  return r;
}

// exchange a's hi-lanes with b's lo-lanes
__device__ __forceinline__ void swap32(u32& a, u32& b) {
  asm("v_permlane32_swap_b32 %0, %1" : "+v"(a), "+v"(b));
}

__device__ __forceinline__ bf16x8 mkfrag(u32 w0, u32 w1, u32 w2, u32 w3) {
  union { u32 u[4]; bf16x8 v; } x;
  x.u[0] = w0; x.u[1] = w1; x.u[2] = w2; x.u[3] = w3;
  return x.v;
}

// ---------------------------------------------------------------------------
// prep_ib_kernel (800 blocks): prep paths (0..287) + ib paths (288..799).
// ---------------------------------------------------------------------------
__global__ __launch_bounds__(256) void prep_ib_kernel(
    const float* __restrict__ w_qkv, const float* __restrict__ w_merge,
    const float* __restrict__ w_proj, const float* __restrict__ b_merge,
    const float* __restrict__ b_proj, u16* __restrict__ wqkvT,
    u16* __restrict__ wptT, u16* __restrict__ wcombT, u16* __restrict__ wmb,
    float* __restrict__ biasc, const float* __restrict__ x,
    const float* __restrict__ w_in, const float* __restrict__ b_in,
    const float* __restrict__ w_out, const float* __restrict__ b_out,
    u16* __restrict__ xb, u16* __restrict__ catb) {
  __shared__ __align__(16) char smem[35456];
  int blk = blockIdx.x, tid = threadIdx.x;
  if (blk < 192) {
    const float* src;
    int lsrc, ldd, r0, c0;
    u16* dst;
    if (blk < 96) {
      src = w_qkv; lsrc = 1536; dst = wqkvT; ldd = 256;
      r0 = (blk & 3) * 64; c0 = (blk >> 2) * 64;
    } else if (blk < 160) {
      int b2 = blk - 96;
      src = w_proj; lsrc = 512; dst = wptT; ldd = 512;
      r0 = (b2 & 7) * 64; c0 = (b2 >> 3) * 64;
    } else {
      int b2 = blk - 160;
      src = w_proj + 512 * 512; lsrc = 512; dst = wcombT + 512; ldd = 768;
      r0 = (b2 & 3) * 64; c0 = (b2 >> 2) * 64;
    }
    u16* Ts = (u16*)smem;  // [64][68]
    int rr = tid >> 4, cc4 = (tid & 15) * 4;
#pragma unroll
    for (int rep = 0; rep < 4; ++rep) {
      int r = rr + rep * 16;
      float4 v = *(const float4*)&src[(size_t)(r0 + r) * lsrc + c0 + cc4];
      su16x4 pk = {f2bf(v.x), f2bf(v.y), f2bf(v.z), f2bf(v.w)};
      *(su16x4*)&Ts[r * 68 + cc4] = pk;
    }
    __syncthreads();
    int c = tid & 63, seg = tid >> 6;
    u16 tmp[16];
#pragma unroll
    for (int k = 0; k < 16; ++k) tmp[k] = Ts[(seg * 16 + k) * 68 + c];
    *(su16x8*)&dst[(size_t)(c0 + c) * ldd + r0 + seg * 16] = *(su16x8*)tmp;
    *(su16x8*)&dst[(size_t)(c0 + c) * ldd + r0 + seg * 16 + 8] =
        *(su16x8*)(tmp + 8);
  } else if (blk < 256) {
    int b2 = blk - 192;
#pragma unroll
    for (int rep = 0; rep < 4; ++rep) {
      int i = b2 * 4096 + rep * 1024 + tid * 4;
      float4 v = *(const float4*)&w_merge[i];
      su16x4 pk = {f2bf(v.x), f2bf(v.y), f2bf(v.z), f2bf(v.w)};
      *(su16x4*)&wmb[i] = pk;
    }
  } else if (blk < 288) {
    int col0 = (blk - 256) * 16;
    float(*red)[17] = (float(*)[17])smem;
    int kr = tid >> 4, cc = tid & 15;
    float s = 0.f;
#pragma unroll 4
    for (int j = 0; j < 32; ++j) {
      int k = kr + j * 16;
      s += b_merge[k] * w_proj[(size_t)k * 512 + col0 + cc];
    }
    red[kr][cc] = s;
    __syncthreads();
    if (kr == 0) {
      float a = b_proj[col0 + cc];
#pragma unroll
      for (int t = 0; t < 16; ++t) a += red[t][cc];
      biasc[col0 + cc] = a;
    }
  } else {
    int ib = blk - 288;
    float* wi = (float*)smem;            // 256
    float* wo = (float*)(smem + 1024);   // 256
    float* bi = (float*)(smem + 2048);   // 16
    float* bo = (float*)(smem + 2112);   // 16
    float(*xs)[260] = (float(*)[260])(smem + 2176);
    float(*hs)[260] = (float(*)[260])(smem + 18816);
    wi[tid] = w_in[tid];
    wo[tid] = w_out[tid];
    if (tid < 16) { bi[tid] = b_in[tid]; bo[tid] = b_out[tid]; }
    size_t blkoff = (size_t)ib * 4096;
#pragma unroll
    for (int i = 0; i < 4; ++i) {
      int f = (tid + i * 256) * 4;
      float4 v = *(const float4*)&x[blkoff + f];
      int tok = f >> 8, p = f & 255;
      *(float4*)&xs[tok][p] = v;
      su16x4 pk = {f2bf(v.x), f2bf(v.y), f2bf(v.z), f2bf(v.w)};
      *(su16x4*)&xb[blkoff + f] = pk;
    }
    __syncthreads();
    int t = tid >> 4, p2 = tid & 15;
#pragma unroll
    for (int p1 = 0; p1 < 16; ++p1) {
      float a = bi[p2];
#pragma unroll
      for (int k = 0; k < 16; ++k) a += xs[t][p1 * 16 + k] * wi[k * 16 + p2];
      hs[t][p1 * 16 + p2] = a / (1.f + __expf(-a));
    }
    __syncthreads();
    size_t tok = (size_t)ib * 16 + t;
#pragma unroll
    for (int p1 = 0; p1 < 16; ++p1) {
      float o = bo[p2];
#pragma unroll
      for (int j = 0; j < 16; ++j) o += hs[t][p1 * 16 + j] * wo[j * 16 + p2];
      catb[tok * 768 + 512 + p1 * 16 + p2] = f2bf(o);
    }
  }
}

// ---------------------------------------------------------------------------
// gemm_bt: C[TM-tile][TN-tile] = A[m][k] @ BT[n][k]^T  (both row-major, k-inner)
// OUTMODE 0: f32 out (+bias). 1: bf16 out via LDS-staged b128 stores (+bias,
// scaleQ multiplies cols<512 by SCALE*log2e). 2: bf16 scatter (small tiles).
// BK=64 K-slabs (2 barriers per slab, register prefetch of next slab).
// LDS rows stride 72 u16: 2-way bank aliasing on frag reads (free).
// ---------------------------------------------------------------------------
template <int TM, int TN, int WGM, int WGN, int OUTMODE>
__global__ __launch_bounds__(256) void gemm_bt(
    const u16* __restrict__ A, int lda, const u16* __restrict__ BT, int ldb,
    int kcount, const float* __restrict__ bias, void* __restrict__ Co, int ldc,
    int scaleQ) {
  constexpr int NROWS = TM + TN;
  constexpr int NLD = NROWS / 32;  // staging passes for a 64-k slab
  constexpr int MT = TM / WGM / 16;
  constexpr int NT = TN / WGN / 16;
  __shared__ __align__(16) u16 S[NROWS * 72];
  int tid = threadIdx.x;
  int lane = tid & 63, wave = tid >> 6;
  int c = lane & 15, g4 = lane >> 4;
  int m0 = blockIdx.y * TM, n0 = blockIdx.x * TN;
  int wm = (wave / WGN) * (TM / WGM), wn = (wave % WGN) * (TN / WGN);
  f32x4 acc[MT][NT];
#pragma unroll
  for (int a = 0; a < MT; ++a)
#pragma unroll
    for (int b = 0; b < NT; ++b) acc[a][b] = zero4();

  su16x8 pre[NLD];
#pragma unroll
  for (int t = 0; t < NLD; ++t) {
    int gsl = t * 256 + tid;
    int row = gsl >> 3, kg = gsl & 7;
    const u16* p = row < TM ? &A[(size_t)(m0 + row) * lda + kg * 8]
                            : &BT[(size_t)(n0 + row - TM) * ldb + kg * 8];
    pre[t] = *(const su16x8*)p;
  }

  for (int kb = 0; kb < kcount; kb += 64) {
    __syncthreads();
#pragma unroll
    for (int t = 0; t < NLD; ++t) {
      int gsl = t * 256 + tid;
      int row = gsl >> 3, kg = gsl & 7;
      *(su16x8*)&S[row * 72 + kg * 8] = pre[t];
    }
    __syncthreads();
    if (kb + 64 < kcount) {
#pragma unroll
      for (int t = 0; t < NLD; ++t) {
        int gsl = t * 256 + tid;
        int row = gsl >> 3, kg = gsl & 7;
        const u16* p =
            row < TM ? &A[(size_t)(m0 + row) * lda + kb + 64 + kg * 8]
                     : &BT[(size_t)(n0 + row - TM) * ldb + kb + 64 + kg * 8];
        pre[t] = *(const su16x8*)p;
      }
    }
#pragma unroll
    for (int kc = 0; kc < 2; ++kc) {
      bf16x8 af[MT], bf[NT];
#pragma unroll
      for (int mt = 0; mt < MT; ++mt)
        af[mt] =
            *(const bf16x8*)&S[(wm + mt * 16 + c) * 72 + kc * 32 + g4 * 8];
#pragma unroll
      for (int nt = 0; nt < NT; ++nt)
        bf[nt] = *(const bf16x8*)&S[(TM + wn + nt * 16 + c) * 72 + kc * 32 +
                                    g4 * 8];
#pragma unroll
      for (int mt = 0; mt < MT; ++mt)
#pragma unroll
        for (int nt = 0; nt < NT; ++nt)
          acc[mt][nt] = mfma16(af[mt], bf[nt], acc[mt][nt]);
    }
  }

  if (OUTMODE == 0) {
    float* Cf = (float*)Co;
#pragma unroll
    for (int nt = 0; nt < NT; ++nt) {
      int col = n0 + wn + nt * 16 + c;
      float bv = bias ? bias[col] : 0.f;
#pragma unroll
      for (int mt = 0; mt < MT; ++mt)
#pragma unroll
        for (int i = 0; i < 4; ++i)
          Cf[(size_t)(m0 + wm + mt * 16 + g4 * 4 + i) * ldc + col] =
              acc[mt][nt][i] + bv;
    }
  } else if (OUTMODE == 2) {
    u16* C16 = (u16*)Co;
#pragma unroll
    for (int nt = 0; nt < NT; ++nt)
#pragma unroll
      for (int mt = 0; mt < MT; ++mt)
#pragma unroll
        for (int i = 0; i < 4; ++i)
          C16[(size_t)(m0 + wm + mt * 16 + g4 * 4 + i) * ldc + n0 + wn +
              nt * 16 + c] = f2bf(acc[mt][nt][i]);
  } else {
    // OUTMODE 1: requires TM==128, TN==128, WGM==2
    u16* C16 = (u16*)Co;
    u16* Cs = S;  // [64][136] per half
    __syncthreads();
#pragma unroll
    for (int half = 0; half < 2; ++half) {
      if ((wave >> 1) == half) {
#pragma unroll
        for (int nt = 0; nt < NT; ++nt) {
          int col = n0 + wn + nt * 16 + c;
          float bv = bias ? bias[col] : 0.f;
          float sc = (scaleQ && col < 512) ? 0.18033688011112042f : 1.f;
#pragma unroll
          for (int mt = 0; mt < MT; ++mt)
#pragma unroll
            for (int i = 0; i < 4; ++i)
              Cs[(mt * 16 + g4 * 4 + i) * 136 + wn + nt * 16 + c] =
                  f2bf((acc[mt][nt][i] + bv) * sc);
        }
      }
      __syncthreads();
      {
        int row = tid >> 2;
#pragma unroll
        for (int t = 0; t < 4; ++t) {
          int gr = (tid & 3) + t * 4;
          u32x4 v = *(const u32x4*)&Cs[row * 136 + gr * 8];
          *(u32x4*)&C16[(size_t)(m0 + half * 64 + row) * ldc + n0 + gr * 8] = v;
        }
      }
      __syncthreads();
    }
  }
}

// ---------------------------------------------------------------------------
// attn_kernel: flash attention in exp2 domain, no running max. (R5, best.)
// 32x32x16 MFMA. S^T = K·Q^T so each lane holds P for its own q-row
// (col=lane&31); P -> bf16 A-frags fully in-register via v_cvt_pk_bf16_f32 +
// permlane32_swap (no P LDS round-trip). K/V LDS double-buffered: 1
// barrier/iter; global prefetch issued right after the barrier, LDS-staged
// after compute. setprio(1) around MFMA clusters. V swizzle &7 both sides.
// LDS 70 KB. 32 q/wave, 128 kv/iter.
// ---------------------------------------------------------------------------
__global__ __launch_bounds__(256, 2) void attn_kernel(
    const u16* __restrict__ qkvb, u16* __restrict__ catb) {
  __shared__ __align__(16) u16 Ks[2 * 9216];  // K [kv=128][d=64 +8], x2 buf
  __shared__ __align__(16) u16 Vs[2 * 8704];  // V^T [d=64][kv-pairs swz], x2
  int tid = threadIdx.x;
  int lane = tid & 63, wave = tid >> 6;
  int l31 = lane & 31, hi = lane >> 5;
  int wq = wave * 32;
  int bh = blockIdx.x & 31, qt = blockIdx.x >> 5;
  int bb = bh >> 3, h = bh & 7;
  size_t base = (size_t)bb * 2048 * 1536;

  // Q fragments (B-operand: col=q=l31, k=hi*8+j), 4 chunks of K=16 over d=64
  bf16x8 qf[4];
  {
    int n = qt * 128 + wq + l31;
    const u16* qp = &qkvb[base + (size_t)n * 1536 + h * 64 + hi * 8];
#pragma unroll
    for (int kc = 0; kc < 4; ++kc) qf[kc] = *(const bf16x8*)(qp + kc * 16);
  }

  f32x16 oacc[2];
#pragma unroll
  for (int dt = 0; dt < 2; ++dt)
#pragma unroll
    for (int r = 0; r < 16; ++r) oacc[dt][r] = 0.f;
  float lsum = 0.f;

  su16x8 kpre[4], v0pre[2], v1pre[2];
  int kv_s = tid >> 3, dg_s = tid & 7;  // staging coords (t adds 32 kv rows)

  auto loadKV = [&](int n0k) {
#pragma unroll
    for (int t = 0; t < 4; ++t)
      kpre[t] = *(const su16x8*)&qkvb[base + (size_t)(n0k + kv_s + t * 32) *
                                                1536 +
                                      512 + h * 64 + dg_s * 8];
#pragma unroll
    for (int t = 0; t < 2; ++t) {
      const u16* vg = &qkvb[base + (size_t)(n0k + (kv_s + t * 32) * 2) * 1536 +
                            1024 + h * 64 + dg_s * 8];
      v0pre[t] = *(const su16x8*)vg;
      v1pre[t] = *(const su16x8*)(vg + 1536);
    }
  };

  auto stage = [&](int buf) {
    u16* ksw = Ks + buf * 9216;
    u32* vw = (u32*)(Vs + buf * 8704);
#pragma unroll
    for (int t = 0; t < 4; ++t)
      *(su16x8*)&ksw[(kv_s + t * 32) * 72 + dg_s * 8] = kpre[t];
#pragma unroll
    for (int t = 0; t < 2; ++t) {
      int kvp = kv_s + t * 32;
      int kvg = kvp >> 2, w2 = kvp & 3;
#pragma unroll
      for (int j = 0; j < 8; ++j) {
        int d = dg_s * 8 + j;
        vw[d * 68 + ((kvg ^ (dg_s & 7)) << 2) + w2] =
            (u32)v0pre[t][j] | ((u32)v1pre[t][j] << 16);
      }
    }
  };

  loadKV(0);
  stage(0);
  for (int kb2 = 0; kb2 < 16; ++kb2) {
    __syncthreads();  // staged writes visible; everyone done with other buf
    int cur = kb2 & 1;
    if (kb2 < 15) loadKV((kb2 + 1) * 128);  // global prefetch, consumed at end
    const u16* ksb = Ks + cur * 9216;
    const u16* vsb = Vs + cur * 8704;
#pragma unroll
    for (int kvt = 0; kvt < 4; ++kvt) {
      // ---- S^T tile = K[32 kv] · Q^T  (A=K row=l31, B=Q col=l31) ----
      bf16x8 kf[4];
#pragma unroll
      for (int kc = 0; kc < 4; ++kc)
        kf[kc] =
            *(const bf16x8*)&ksb[(kvt * 32 + l31) * 72 + kc * 16 + hi * 8];
      f32x16 sacc;
#pragma unroll
      for (int r = 0; r < 16; ++r) sacc[r] = 0.f;
      __builtin_amdgcn_s_setprio(1);
#pragma unroll
      for (int kc = 0; kc < 4; ++kc) sacc = mfma32(kf[kc], qf[kc], sacc);
      __builtin_amdgcn_s_setprio(0);
      // ---- P = exp2(S^T): lane owns q=l31, kv t=(r&3)+8*(r>>2)+4*hi ----
      float p[16];
#pragma unroll
      for (int r = 0; r < 16; ++r) p[r] = fexp2(sacc[r]);
      lsum += ((((p[0] + p[1]) + (p[2] + p[3])) +
                ((p[4] + p[5]) + (p[6] + p[7]))) +
               (((p[8] + p[9]) + (p[10] + p[11])) +
                ((p[12] + p[13]) + (p[14] + p[15]))));
      // ---- in-register P -> A-frag bf16 (cvt_pk + permlane32_swap) ----
      u32 a0 = pkbf(p[0], p[1]), b0 = pkbf(p[4], p[5]);
      u32 a1 = pkbf(p[2], p[3]), b1 = pkbf(p[6], p[7]);
      u32 a2 = pkbf(p[8], p[9]), b2 = pkbf(p[12], p[13]);
      u32 a3 = pkbf(p[10], p[11]), b3 = pkbf(p[14], p[15]);
      swap32(a0, b0);
      swap32(a1, b1);
      swap32(a2, b2);
      swap32(a3, b3);
      bf16x8 pf0 = mkfrag(a0, a1, b0, b1);  // kv chunk kvt*32 + [0,16)
      bf16x8 pf1 = mkfrag(a2, a3, b2, b3);  // kv chunk kvt*32 + [16,32)
      // ---- O += P @ V  (B=V col=d=l31, k=kv) ----
      __builtin_amdgcn_s_setprio(1);
#pragma unroll
      for (int kc2 = 0; kc2 < 2; ++kc2) {
        int g = (kvt * 2 + kc2) * 2 + hi;  // 8-kv granule index
#pragma unroll
        for (int dt = 0; dt < 2; ++dt) {
          int d = dt * 32 + l31;
          bf16x8 vf =
              *(const bf16x8*)&vsb[d * 136 + ((g ^ ((d >> 3) & 7)) << 3)];
          oacc[dt] = mfma32(kc2 ? pf1 : pf0, vf, oacc[dt]);
        }
      }
      __builtin_amdgcn_s_setprio(0);
    }
    if (kb2 < 15) stage(cur ^ 1);  // vmcnt wait lands here, after compute
  }
  lsum += __shfl_xor(lsum, 32);
#pragma unroll
  for (int r = 0; r < 16; ++r) {
    int qrow = (r & 3) + 8 * (r >> 2) + 4 * hi;
    float linv = 1.f / __shfl(lsum, qrow);
    size_t n = (size_t)(bb * 2048 + qt * 128 + wq + qrow);
    u16* cp = &catb[n * 768 + h * 64];
    cp[l31] = f2bf(oacc[0][r] * linv);
    cp[32 + l31] = f2bf(oacc[1][r] * linv);
  }
}

// ---------------------------------------------------------------------------
extern "C" void kernel_launch(void* const* d_in, const int* in_sizes, int n_in,
                              void* d_out, int out_size, void* d_ws,
                              size_t ws_size, hipStream_t stream) {
  const float* x = (const float*)d_in[0];
  const float* w_qkv = (const float*)d_in[1];
  const float* b_qkv = (const float*)d_in[2];
  const float* w_in = (const float*)d_in[3];
  const float* b_in = (const float*)d_in[4];
  const float* w_out = (const float*)d_in[5];
  const float* b_out = (const float*)d_in[6];
  const float* w_merge = (const float*)d_in[7];
  const float* b_merge = (const float*)d_in[8];
  const float* w_proj = (const float*)d_in[9];
  const float* b_proj = (const float*)d_in[10];

  char* ws = (char*)d_ws;
  u16* xb = (u16*)(ws + 0);               //  4,194,304 B
  u16* qkvb = (u16*)(ws + 4194304);       // 25,165,824 B
  u16* catb = (u16*)(ws + 29360128);      // 12,582,912 B
  u16* wqkvT = (u16*)(ws + 41943040);     //    786,432 B  [1536][256]
  u16* wptT = (u16*)(ws + 42729472);      //    524,288 B  [512][512]
  u16* wmb = (u16*)(ws + 43253760);       //    524,288 B  [512][512]
  u16* wcombT = (u16*)(ws + 43778048);    //    786,432 B  [512][768]
  float* biasc = (float*)(ws + 44564480); //      2,048 B

  prep_ib_kernel<<<800, 256, 0, stream>>>(w_qkv, w_merge, w_proj, b_merge,
                                          b_proj, wqkvT, wptT, wcombT, wmb,
                                          biasc, x, w_in, b_in, w_out, b_out,
                                          xb, catb);
  // qkv = x @ w_qkv + b_qkv; q scaled by SCALE*log2e in epilogue
  gemm_bt<128, 128, 2, 2, 1><<<dim3(12, 64), 256, 0, stream>>>(
      xb, 256, wqkvT, 256, 256, b_qkv, (void*)qkvb, 1536, 1);
  // wcombT[:, :512] = wptT @ w_merge  (= (w_merge @ w_proj_top)^T)
  gemm_bt<64, 64, 2, 2, 2><<<dim3(8, 8), 256, 0, stream>>>(
      wptT, 512, wmb, 512, 512, nullptr, (void*)wcombT, 768, 0);
  attn_kernel<<<512, 256, 0, stream>>>(qkvb, catb);
  // out = catb @ wcombT^T + biasc  (fp32)
  gemm_bt<128, 64, 4, 1, 0><<<dim3(8, 64), 256, 0, stream>>>(
      catb, 768, wcombT, 768, 768, biasc, d_out, 512, 0);
}

// Round 11
// 171.619 us; speedup vs baseline: 1.0467x; 1.0467x over previous
//
#include <hip/hip_runtime.h>

// ---------------------------------------------------------------------------
// MSAAttention fused pipeline (MI355X / gfx950), bf16 MFMA throughout.
//
// out = concat[softmax(qk^T*s)v @ w_merge + b_merge, ib] @ w_proj + b_proj
// Folded: wcombT holds (w_merge@w_proj_top)^T and w_proj_bot^T — the merge
// GEMM is deleted; biasc = b_merge@w_proj_top + b_proj.
// SCALE*log2e folded into q; softmax in exp2 domain, no max-subtraction.
// attn: R5 structure verbatim (robust best 47.0 µs across 6 perturbations).
// gemm: R5 BK=32 body (BK=64 and dbuf variants both regressed), refactored
// into a __device__ template; gemm_small MERGED into the gemm_qkv dispatch
// (832 blocks) — standalone it ran 64 blocks on an otherwise-idle GPU and
// cost a launch gap. 4 dispatches total (was 5).
// ---------------------------------------------------------------------------

typedef unsigned short u16;
typedef unsigned int u32;
typedef __bf16 bf16x8 __attribute__((ext_vector_type(8)));
typedef u16 su16x8 __attribute__((ext_vector_type(8)));
typedef u16 su16x4 __attribute__((ext_vector_type(4)));
typedef u32 u32x4 __attribute__((ext_vector_type(4)));
typedef float f32x4 __attribute__((ext_vector_type(4)));
typedef float f32x16 __attribute__((ext_vector_type(16)));

__device__ __forceinline__ u16 f2bf(float f) {
  union { __bf16 h; u16 u; } v;
  v.h = (__bf16)f;
  return v.u;
}

__device__ __forceinline__ float fexp2(float x) {
#if __has_builtin(__builtin_amdgcn_exp2f)
  return __builtin_amdgcn_exp2f(x);
#else
  return __expf(x * 0.6931471805599453f);
#endif
}

__device__ __forceinline__ f32x4 zero4() {
  f32x4 v = {0.f, 0.f, 0.f, 0.f};
  return v;
}

__device__ __forceinline__ f32x4 mfma16(bf16x8 a, bf16x8 b, f32x4 c) {
  return __builtin_amdgcn_mfma_f32_16x16x32_bf16(a, b, c, 0, 0, 0);
}

__device__ __forceinline__ f32x16 mfma32(bf16x8 a, bf16x8 b, f32x16 c) {
  return __builtin_amdgcn_mfma_f32_32x32x16_bf16(a, b, c, 0, 0, 0);
}

// pack two f32 -> one u32 of two bf16 (lo = a, hi = b)
__device__ __forceinline__ u32 pkbf(float a, float b) {
  u32 r;
  asm("v_cvt_pk_bf16_f32 %0, %1, %2" : "=v"(r) : "v"(a), "v"(b));
  return r;
}

// exchange a's hi-lanes with b's lo-lanes
__device__ __forceinline__ void swap32(u32& a, u32& b) {
  asm("v_permlane32_swap_b32 %0, %1" : "+v"(a), "+v"(b));
}

__device__ __forceinline__ bf16x8 mkfrag(u32 w0, u32 w1, u32 w2, u32 w3) {
  union { u32 u[4]; bf16x8 v; } x;
  x.u[0] = w0; x.u[1] = w1; x.u[2] = w2; x.u[3] = w3;
  return x.v;
}

// ---------------------------------------------------------------------------
// prep_ib_kernel (800 blocks): prep paths (0..287) + ib paths (288..799).
// ---------------------------------------------------------------------------
__global__ __launch_bounds__(256) void prep_ib_kernel(
    const float* __restrict__ w_qkv, const float* __restrict__ w_merge,
    const float* __restrict__ w_proj, const float* __restrict__ b_merge,
    const float* __restrict__ b_proj, u16* __restrict__ wqkvT,
    u16* __restrict__ wptT, u16* __restrict__ wcombT, u16* __restrict__ wmb,
    float* __restrict__ biasc, const float* __restrict__ x,
    const float* __restrict__ w_in, const float* __restrict__ b_in,
    const float* __restrict__ w_out, const float* __restrict__ b_out,
    u16* __restrict__ xb, u16* __restrict__ catb) {
  __shared__ __align__(16) char smem[35456];
  int blk = blockIdx.x, tid = threadIdx.x;
  if (blk < 192) {
    const float* src;
    int lsrc, ldd, r0, c0;
    u16* dst;
    if (blk < 96) {
      src = w_qkv; lsrc = 1536; dst = wqkvT; ldd = 256;
      r0 = (blk & 3) * 64; c0 = (blk >> 2) * 64;
    } else if (blk < 160) {
      int b2 = blk - 96;
      src = w_proj; lsrc = 512; dst = wptT; ldd = 512;
      r0 = (b2 & 7) * 64; c0 = (b2 >> 3) * 64;
    } else {
      int b2 = blk - 160;
      src = w_proj + 512 * 512; lsrc = 512; dst = wcombT + 512; ldd = 768;
      r0 = (b2 & 3) * 64; c0 = (b2 >> 2) * 64;
    }
    u16* Ts = (u16*)smem;  // [64][68]
    int rr = tid >> 4, cc4 = (tid & 15) * 4;
#pragma unroll
    for (int rep = 0; rep < 4; ++rep) {
      int r = rr + rep * 16;
      float4 v = *(const float4*)&src[(size_t)(r0 + r) * lsrc + c0 + cc4];
      su16x4 pk = {f2bf(v.x), f2bf(v.y), f2bf(v.z), f2bf(v.w)};
      *(su16x4*)&Ts[r * 68 + cc4] = pk;
    }
    __syncthreads();
    int c = tid & 63, seg = tid >> 6;
    u16 tmp[16];
#pragma unroll
    for (int k = 0; k < 16; ++k) tmp[k] = Ts[(seg * 16 + k) * 68 + c];
    *(su16x8*)&dst[(size_t)(c0 + c) * ldd + r0 + seg * 16] = *(su16x8*)tmp;
    *(su16x8*)&dst[(size_t)(c0 + c) * ldd + r0 + seg * 16 + 8] =
        *(su16x8*)(tmp + 8);
  } else if (blk < 256) {
    int b2 = blk - 192;
#pragma unroll
    for (int rep = 0; rep < 4; ++rep) {
      int i = b2 * 4096 + rep * 1024 + tid * 4;
      float4 v = *(const float4*)&w_merge[i];
      su16x4 pk = {f2bf(v.x), f2bf(v.y), f2bf(v.z), f2bf(v.w)};
      *(su16x4*)&wmb[i] = pk;
    }
  } else if (blk < 288) {
    int col0 = (blk - 256) * 16;
    float(*red)[17] = (float(*)[17])smem;
    int kr = tid >> 4, cc = tid & 15;
    float s = 0.f;
#pragma unroll 4
    for (int j = 0; j < 32; ++j) {
      int k = kr + j * 16;
      s += b_merge[k] * w_proj[(size_t)k * 512 + col0 + cc];
    }
    red[kr][cc] = s;
    __syncthreads();
    if (kr == 0) {
      float a = b_proj[col0 + cc];
#pragma unroll
      for (int t = 0; t < 16; ++t) a += red[t][cc];
      biasc[col0 + cc] = a;
    }
  } else {
    int ib = blk - 288;
    float* wi = (float*)smem;            // 256
    float* wo = (float*)(smem + 1024);   // 256
    float* bi = (float*)(smem + 2048);   // 16
    float* bo = (float*)(smem + 2112);   // 16
    float(*xs)[260] = (float(*)[260])(smem + 2176);
    float(*hs)[260] = (float(*)[260])(smem + 18816);
    wi[tid] = w_in[tid];
    wo[tid] = w_out[tid];
    if (tid < 16) { bi[tid] = b_in[tid]; bo[tid] = b_out[tid]; }
    size_t blkoff = (size_t)ib * 4096;
#pragma unroll
    for (int i = 0; i < 4; ++i) {
      int f = (tid + i * 256) * 4;
      float4 v = *(const float4*)&x[blkoff + f];
      int tok = f >> 8, p = f & 255;
      *(float4*)&xs[tok][p] = v;
      su16x4 pk = {f2bf(v.x), f2bf(v.y), f2bf(v.z), f2bf(v.w)};
      *(su16x4*)&xb[blkoff + f] = pk;
    }
    __syncthreads();
    int t = tid >> 4, p2 = tid & 15;
#pragma unroll
    for (int p1 = 0; p1 < 16; ++p1) {
      float a = bi[p2];
#pragma unroll
      for (int k = 0; k < 16; ++k) a += xs[t][p1 * 16 + k] * wi[k * 16 + p2];
      hs[t][p1 * 16 + p2] = a / (1.f + __expf(-a));
    }
    __syncthreads();
    size_t tok = (size_t)ib * 16 + t;
#pragma unroll
    for (int p1 = 0; p1 < 16; ++p1) {
      float o = bo[p2];
#pragma unroll
      for (int j = 0; j < 16; ++j) o += hs[t][p1 * 16 + j] * wo[j * 16 + p2];
      catb[tok * 768 + 512 + p1 * 16 + p2] = f2bf(o);
    }
  }
}

// ---------------------------------------------------------------------------
// gemm_body: C[TM-tile][TN-tile] = A[m][k] @ BT[n][k]^T (row-major, k-inner).
// R5-proven loop: BK=32, single LDS buffer, 2 barriers/slab, register
// prefetch of next slab. OUTMODE 0: f32 out (+bias). 1: bf16 out via
// LDS-staged b128 stores (+bias, scaleQ scales cols<512). 2: bf16 scatter.
// ---------------------------------------------------------------------------
template <int TM, int TN, int WGM, int WGN, int OUTMODE>
__device__ __forceinline__ void gemm_body(
    const u16* __restrict__ A, int lda, const u16* __restrict__ BT, int ldb,
    int kcount, const float* __restrict__ bias, void* __restrict__ Co, int ldc,
    int scaleQ, u16* S, int bx, int by) {
  constexpr int NROWS = TM + TN;
  constexpr int NLD = NROWS / 64;
  constexpr int MT = TM / WGM / 16;
  constexpr int NT = TN / WGN / 16;
  int tid = threadIdx.x;
  int lane = tid & 63, wave = tid >> 6;
  int c = lane & 15, g4 = lane >> 4;
  int m0 = by * TM, n0 = bx * TN;
  int wm = (wave / WGN) * (TM / WGM), wn = (wave % WGN) * (TN / WGN);
  f32x4 acc[MT][NT];
#pragma unroll
  for (int a = 0; a < MT; ++a)
#pragma unroll
    for (int b = 0; b < NT; ++b) acc[a][b] = zero4();

  su16x8 pre[NLD];
#pragma unroll
  for (int t = 0; t < NLD; ++t) {
    int gsl = t * 256 + tid;
    int row = gsl >> 2, kg = gsl & 3;
    const u16* p = row < TM ? &A[(size_t)(m0 + row) * lda + kg * 8]
                            : &BT[(size_t)(n0 + row - TM) * ldb + kg * 8];
    pre[t] = *(const su16x8*)p;
  }

  for (int kb = 0; kb < kcount; kb += 32) {
    __syncthreads();
#pragma unroll
    for (int t = 0; t < NLD; ++t) {
      int gsl = t * 256 + tid;
      int row = gsl >> 2, kg = gsl & 3;
      *(su16x8*)&S[row * 40 + kg * 8] = pre[t];
    }
    __syncthreads();
    if (kb + 32 < kcount) {
#pragma unroll
      for (int t = 0; t < NLD; ++t) {
        int gsl = t * 256 + tid;
        int row = gsl >> 2, kg = gsl & 3;
        const u16* p =
            row < TM ? &A[(size_t)(m0 + row) * lda + kb + 32 + kg * 8]
                     : &BT[(size_t)(n0 + row - TM) * ldb + kb + 32 + kg * 8];
        pre[t] = *(const su16x8*)p;
      }
    }
    bf16x8 af[MT], bf[NT];
#pragma unroll
    for (int mt = 0; mt < MT; ++mt)
      af[mt] = *(const bf16x8*)&S[(wm + mt * 16 + c) * 40 + g4 * 8];
#pragma unroll
    for (int nt = 0; nt < NT; ++nt)
      bf[nt] = *(const bf16x8*)&S[(TM + wn + nt * 16 + c) * 40 + g4 * 8];
#pragma unroll
    for (int mt = 0; mt < MT; ++mt)
#pragma unroll
      for (int nt = 0; nt < NT; ++nt)
        acc[mt][nt] = mfma16(af[mt], bf[nt], acc[mt][nt]);
  }

  if (OUTMODE == 0) {
    float* Cf = (float*)Co;
#pragma unroll
    for (int nt = 0; nt < NT; ++nt) {
      int col = n0 + wn + nt * 16 + c;
      float bv = bias ? bias[col] : 0.f;
#pragma unroll
      for (int mt = 0; mt < MT; ++mt)
#pragma unroll
        for (int i = 0; i < 4; ++i)
          Cf[(size_t)(m0 + wm + mt * 16 + g4 * 4 + i) * ldc + col] =
              acc[mt][nt][i] + bv;
    }
  } else if (OUTMODE == 2) {
    u16* C16 = (u16*)Co;
#pragma unroll
    for (int nt = 0; nt < NT; ++nt)
#pragma unroll
      for (int mt = 0; mt < MT; ++mt)
#pragma unroll
        for (int i = 0; i < 4; ++i)
          C16[(size_t)(m0 + wm + mt * 16 + g4 * 4 + i) * ldc + n0 + wn +
              nt * 16 + c] = f2bf(acc[mt][nt][i]);
  } else {
    // OUTMODE 1: requires TM==128, TN==128, WGM==2
    u16* C16 = (u16*)Co;
    u16* Cs = S;  // [64][136] per half
    __syncthreads();
#pragma unroll
    for (int half = 0; half < 2; ++half) {
      if ((wave >> 1) == half) {
#pragma unroll
        for (int nt = 0; nt < NT; ++nt) {
          int col = n0 + wn + nt * 16 + c;
          float bv = bias ? bias[col] : 0.f;
          float sc = (scaleQ && col < 512) ? 0.18033688011112042f : 1.f;
#pragma unroll
          for (int mt = 0; mt < MT; ++mt)
#pragma unroll
            for (int i = 0; i < 4; ++i)
              Cs[(mt * 16 + g4 * 4 + i) * 136 + wn + nt * 16 + c] =
                  f2bf((acc[mt][nt][i] + bv) * sc);
        }
      }
      __syncthreads();
      {
        int row = tid >> 2;
#pragma unroll
        for (int t = 0; t < 4; ++t) {
          int gr = (tid & 3) + t * 4;
          u32x4 v = *(const u32x4*)&Cs[row * 136 + gr * 8];
          *(u32x4*)&C16[(size_t)(m0 + half * 64 + row) * ldc + n0 + gr * 8] = v;
        }
      }
      __syncthreads();
    }
  }
}

// qkv GEMM (blocks 0..767: 12 x 64 tiles) + small wcombT GEMM (768..831).
__global__ __launch_bounds__(256) void gemm_qkv_small(
    const u16* __restrict__ xb, const u16* __restrict__ wqkvT,
    const float* __restrict__ b_qkv, u16* __restrict__ qkvb,
    const u16* __restrict__ wptT, const u16* __restrict__ wmb,
    u16* __restrict__ wcombT) {
  __shared__ __align__(16) u16 S[256 * 40];
  int bid = blockIdx.x;
  if (bid < 768) {
    gemm_body<128, 128, 2, 2, 1>(xb, 256, wqkvT, 256, 256, b_qkv,
                                 (void*)qkvb, 1536, 1, S, bid % 12, bid / 12);
  } else {
    int b2 = bid - 768;
    gemm_body<64, 64, 2, 2, 2>(wptT, 512, wmb, 512, 512, nullptr,
                               (void*)wcombT, 768, 0, S, b2 & 7, b2 >> 3);
  }
}

// out-proj GEMM wrapper
__global__ __launch_bounds__(256) void gemm_out(
    const u16* __restrict__ catb, const u16* __restrict__ wcombT,
    const float* __restrict__ biasc, void* __restrict__ Co) {
  __shared__ __align__(16) u16 S[192 * 40];
  gemm_body<128, 64, 4, 1, 0>(catb, 768, wcombT, 768, 768, biasc, Co, 512, 0,
                              S, blockIdx.x, blockIdx.y);
}

// ---------------------------------------------------------------------------
// attn_kernel: flash attention in exp2 domain, no running max. (R5, best.)
// 32x32x16 MFMA. S^T = K·Q^T so each lane holds P for its own q-row
// (col=lane&31); P -> bf16 A-frags fully in-register via v_cvt_pk_bf16_f32 +
// permlane32_swap (no P LDS round-trip). K/V LDS double-buffered: 1
// barrier/iter; global prefetch issued right after the barrier, LDS-staged
// after compute. setprio(1) around MFMA clusters. V swizzle &7 both sides.
// LDS 70 KB. 32 q/wave, 128 kv/iter.
// ---------------------------------------------------------------------------
__global__ __launch_bounds__(256, 2) void attn_kernel(
    const u16* __restrict__ qkvb, u16* __restrict__ catb) {
  __shared__ __align__(16) u16 Ks[2 * 9216];  // K [kv=128][d=64 +8], x2 buf
  __shared__ __align__(16) u16 Vs[2 * 8704];  // V^T [d=64][kv-pairs swz], x2
  int tid = threadIdx.x;
  int lane = tid & 63, wave = tid >> 6;
  int l31 = lane & 31, hi = lane >> 5;
  int wq = wave * 32;
  int bh = blockIdx.x & 31, qt = blockIdx.x >> 5;
  int bb = bh >> 3, h = bh & 7;
  size_t base = (size_t)bb * 2048 * 1536;

  // Q fragments (B-operand: col=q=l31, k=hi*8+j), 4 chunks of K=16 over d=64
  bf16x8 qf[4];
  {
    int n = qt * 128 + wq + l31;
    const u16* qp = &qkvb[base + (size_t)n * 1536 + h * 64 + hi * 8];
#pragma unroll
    for (int kc = 0; kc < 4; ++kc) qf[kc] = *(const bf16x8*)(qp + kc * 16);
  }

  f32x16 oacc[2];
#pragma unroll
  for (int dt = 0; dt < 2; ++dt)
#pragma unroll
    for (int r = 0; r < 16; ++r) oacc[dt][r] = 0.f;
  float lsum = 0.f;

  su16x8 kpre[4], v0pre[2], v1pre[2];
  int kv_s = tid >> 3, dg_s = tid & 7;  // staging coords (t adds 32 kv rows)

  auto loadKV = [&](int n0k) {
#pragma unroll
    for (int t = 0; t < 4; ++t)
      kpre[t] = *(const su16x8*)&qkvb[base + (size_t)(n0k + kv_s + t * 32) *
                                                1536 +
                                      512 + h * 64 + dg_s * 8];
#pragma unroll
    for (int t = 0; t < 2; ++t) {
      const u16* vg = &qkvb[base + (size_t)(n0k + (kv_s + t * 32) * 2) * 1536 +
                            1024 + h * 64 + dg_s * 8];
      v0pre[t] = *(const su16x8*)vg;
      v1pre[t] = *(const su16x8*)(vg + 1536);
    }
  };

  auto stage = [&](int buf) {
    u16* ksw = Ks + buf * 9216;
    u32* vw = (u32*)(Vs + buf * 8704);
#pragma unroll
    for (int t = 0; t < 4; ++t)
      *(su16x8*)&ksw[(kv_s + t * 32) * 72 + dg_s * 8] = kpre[t];
#pragma unroll
    for (int t = 0; t < 2; ++t) {
      int kvp = kv_s + t * 32;
      int kvg = kvp >> 2, w2 = kvp & 3;
#pragma unroll
      for (int j = 0; j < 8; ++j) {
        int d = dg_s * 8 + j;
        vw[d * 68 + ((kvg ^ (dg_s & 7)) << 2) + w2] =
            (u32)v0pre[t][j] | ((u32)v1pre[t][j] << 16);
      }
    }
  };

  loadKV(0);
  stage(0);
  for (int kb2 = 0; kb2 < 16; ++kb2) {
    __syncthreads();  // staged writes visible; everyone done with other buf
    int cur = kb2 & 1;
    if (kb2 < 15) loadKV((kb2 + 1) * 128);  // global prefetch, consumed at end
    const u16* ksb = Ks + cur * 9216;
    const u16* vsb = Vs + cur * 8704;
#pragma unroll
    for (int kvt = 0; kvt < 4; ++kvt) {
      // ---- S^T tile = K[32 kv] · Q^T  (A=K row=l31, B=Q col=l31) ----
      bf16x8 kf[4];
#pragma unroll
      for (int kc = 0; kc < 4; ++kc)
        kf[kc] =
            *(const bf16x8*)&ksb[(kvt * 32 + l31) * 72 + kc * 16 + hi * 8];
      f32x16 sacc;
#pragma unroll
      for (int r = 0; r < 16; ++r) sacc[r] = 0.f;
      __builtin_amdgcn_s_setprio(1);
#pragma unroll
      for (int kc = 0; kc < 4; ++kc) sacc = mfma32(kf[kc], qf[kc], sacc);
      __builtin_amdgcn_s_setprio(0);
      // ---- P = exp2(S^T): lane owns q=l31, kv t=(r&3)+8*(r>>2)+4*hi ----
      float p[16];
#pragma unroll
      for (int r = 0; r < 16; ++r) p[r] = fexp2(sacc[r]);
      lsum += ((((p[0] + p[1]) + (p[2] + p[3])) +
                ((p[4] + p[5]) + (p[6] + p[7]))) +
               (((p[8] + p[9]) + (p[10] + p[11])) +
                ((p[12] + p[13]) + (p[14] + p[15]))));
      // ---- in-register P -> A-frag bf16 (cvt_pk + permlane32_swap) ----
      u32 a0 = pkbf(p[0], p[1]), b0 = pkbf(p[4], p[5]);
      u32 a1 = pkbf(p[2], p[3]), b1 = pkbf(p[6], p[7]);
      u32 a2 = pkbf(p[8], p[9]), b2 = pkbf(p[12], p[13]);
      u32 a3 = pkbf(p[10], p[11]), b3 = pkbf(p[14], p[15]);
      swap32(a0, b0);
      swap32(a1, b1);
      swap32(a2, b2);
      swap32(a3, b3);
      bf16x8 pf0 = mkfrag(a0, a1, b0, b1);  // kv chunk kvt*32 + [0,16)
      bf16x8 pf1 = mkfrag(a2, a3, b2, b3);  // kv chunk kvt*32 + [16,32)
      // ---- O += P @ V  (B=V col=d=l31, k=kv) ----
      __builtin_amdgcn_s_setprio(1);
#pragma unroll
      for (int kc2 = 0; kc2 < 2; ++kc2) {
        int g = (kvt * 2 + kc2) * 2 + hi;  // 8-kv granule index
#pragma unroll
        for (int dt = 0; dt < 2; ++dt) {
          int d = dt * 32 + l31;
          bf16x8 vf =
              *(const bf16x8*)&vsb[d * 136 + ((g ^ ((d >> 3) & 7)) << 3)];
          oacc[dt] = mfma32(kc2 ? pf1 : pf0, vf, oacc[dt]);
        }
      }
      __builtin_amdgcn_s_setprio(0);
    }
    if (kb2 < 15) stage(cur ^ 1);  // vmcnt wait lands here, after compute
  }
  lsum += __shfl_xor(lsum, 32);
#pragma unroll
  for (int r = 0; r < 16; ++r) {
    int qrow = (r & 3) + 8 * (r >> 2) + 4 * hi;
    float linv = 1.f / __shfl(lsum, qrow);
    size_t n = (size_t)(bb * 2048 + qt * 128 + wq + qrow);
    u16* cp = &catb[n * 768 + h * 64];
    cp[l31] = f2bf(oacc[0][r] * linv);
    cp[32 + l31] = f2bf(oacc[1][r] * linv);
  }
}

// ---------------------------------------------------------------------------
extern "C" void kernel_launch(void* const* d_in, const int* in_sizes, int n_in,
                              void* d_out, int out_size, void* d_ws,
                              size_t ws_size, hipStream_t stream) {
  const float* x = (const float*)d_in[0];
  const float* w_qkv = (const float*)d_in[1];
  const float* b_qkv = (const float*)d_in[2];
  const float* w_in = (const float*)d_in[3];
  const float* b_in = (const float*)d_in[4];
  const float* w_out = (const float*)d_in[5];
  const float* b_out = (const float*)d_in[6];
  const float* w_merge = (const float*)d_in[7];
  const float* b_merge = (const float*)d_in[8];
  const float* w_proj = (const float*)d_in[9];
  const float* b_proj = (const float*)d_in[10];

  char* ws = (char*)d_ws;
  u16* xb = (u16*)(ws + 0);               //  4,194,304 B
  u16* qkvb = (u16*)(ws + 4194304);       // 25,165,824 B
  u16* catb = (u16*)(ws + 29360128);      // 12,582,912 B
  u16* wqkvT = (u16*)(ws + 41943040);     //    786,432 B  [1536][256]
  u16* wptT = (u16*)(ws + 42729472);      //    524,288 B  [512][512]
  u16* wmb = (u16*)(ws + 43253760);       //    524,288 B  [512][512]
  u16* wcombT = (u16*)(ws + 43778048);    //    786,432 B  [512][768]
  float* biasc = (float*)(ws + 44564480); //      2,048 B

  prep_ib_kernel<<<800, 256, 0, stream>>>(w_qkv, w_merge, w_proj, b_merge,
                                          b_proj, wqkvT, wptT, wcombT, wmb,
                                          biasc, x, w_in, b_in, w_out, b_out,
                                          xb, catb);
  // qkv = x @ w_qkv + b_qkv (q scaled by SCALE*log2e in epilogue)
  // + wcombT[:, :512] = wptT @ w_merge, merged into one dispatch
  gemm_qkv_small<<<832, 256, 0, stream>>>(xb, wqkvT, b_qkv, qkvb, wptT, wmb,
                                          wcombT);
  attn_kernel<<<512, 256, 0, stream>>>(qkvb, catb);
  // out = catb @ wcombT^T + biasc  (fp32)
  gemm_out<<<dim3(8, 64), 256, 0, stream>>>(catb, wcombT, biasc, d_out);
}